// Round 9
// baseline (1716.833 us; speedup 1.0000x reference)
//
#include <hip/hip_runtime.h>
#include <hip/hip_bf16.h>

constexpr int Dc = 128;   // feature dim
constexpr int NG = 32;    // num graphs / batch size

// ---- sentinel: encode a diagnostic code in the output magnitude ----
__global__ void k_sentinel(float* __restrict__ out, float val, int n){
  int i = blockIdx.x*256 + threadIdx.x;
  if (i < n) out[i] = val;
}

// ---- init: q = b_img, deg = 1.0 (self-loop weight), pooled/cnt = 0, qi = b_i, cntN = 0 ----
__global__ void k_init(const float* __restrict__ b_img, float* __restrict__ q,
                       float* __restrict__ deg, float* __restrict__ pooled,
                       const float* __restrict__ b_i, float* __restrict__ qi,
                       int* __restrict__ cntN, int BI, int IMG, int N){
  int i = blockIdx.x*256 + threadIdx.x;
  if (i < BI) q[i] = b_img[i % IMG];
  if (i < N){ deg[i] = 1.0f; cntN[i] = 0; }
  if (i < NG*Dc + NG) pooled[i] = 0.f;   // pooled followed by cnt
  if (i < NG*Dc) qi[i] = b_i[i & (Dc-1)];
}

// ---- x0 = node_emb[node_ids] ----
__global__ void k_gather(const float* __restrict__ emb, const int* __restrict__ ids,
                         float* __restrict__ x, int ND){
  int i = blockIdx.x*256 + threadIdx.x;
  if (i >= ND) return;
  int n = i >> 7, d = i & (Dc-1);
  x[i] = emb[(size_t)ids[n]*Dc + d];
}

// ---- deg[dst] += ew ; count in-edges per node ----
__global__ void k_deg2(const int* __restrict__ dst, const float* __restrict__ ew,
                       float* __restrict__ deg, int* __restrict__ cntN, int E){
  int e = blockIdx.x*256 + threadIdx.x;
  if (e >= E) return;
  int d = dst[e];
  atomicAdd(&deg[d], ew[e]);
  atomicAdd(&cntN[d], 1);
}

// ---- dis = rsqrt(deg) in place (deg >= 1 due to self-loops) ----
__global__ void k_dis(float* __restrict__ deg, int N){
  int i = blockIdx.x*256 + threadIdx.x;
  if (i < N) deg[i] = rsqrtf(deg[i]);
}

// ==== CSR build: 3-kernel exclusive scan over cntN, then fill ====
__global__ __launch_bounds__(256) void k_scan_partial(const int* __restrict__ cnt,
        int* __restrict__ bsum, int N){
  __shared__ int red[256];
  int t = threadIdx.x, i = blockIdx.x*256 + t;
  red[t] = (i < N) ? cnt[i] : 0;
  __syncthreads();
  for (int s = 128; s > 0; s >>= 1){ if (t < s) red[t] += red[t+s]; __syncthreads(); }
  if (t == 0) bsum[blockIdx.x] = red[0];
}

__global__ __launch_bounds__(256) void k_scan_bsum(int* __restrict__ bsum, int nb,
        int* __restrict__ row_start, int N, int E){
  __shared__ int sc[256];
  int t = threadIdx.x;
  int orig = (t < nb) ? bsum[t] : 0;
  sc[t] = orig;
  __syncthreads();
  for (int off = 1; off < 256; off <<= 1){
    int v = (t >= off) ? sc[t-off] : 0;
    __syncthreads();
    sc[t] += v;
    __syncthreads();
  }
  if (t < nb) bsum[t] = sc[t] - orig;   // exclusive
  if (t == 0) row_start[N] = E;
}

__global__ __launch_bounds__(256) void k_scan_final(const int* __restrict__ cnt,
        const int* __restrict__ bsum, int* __restrict__ row_start,
        int* __restrict__ cursor, int N){
  __shared__ int sc[256];
  int t = threadIdx.x, i = blockIdx.x*256 + t;
  int orig = (i < N) ? cnt[i] : 0;
  sc[t] = orig;
  __syncthreads();
  for (int off = 1; off < 256; off <<= 1){
    int v = (t >= off) ? sc[t-off] : 0;
    __syncthreads();
    sc[t] += v;
    __syncthreads();
  }
  if (i < N){
    int ex = bsum[blockIdx.x] + sc[t] - orig;
    row_start[i] = ex;
    cursor[i]    = ex;
  }
}

// ---- fill CSR: es[pos]=src, wn[pos]=dis[src]*ew*dis[dst] ----
__global__ void k_fill(const int* __restrict__ src, const int* __restrict__ dst,
        const float* __restrict__ ew, const float* __restrict__ dis,
        int* __restrict__ cursor, int* __restrict__ es, float* __restrict__ wn, int E){
  int e = blockIdx.x*256 + threadIdx.x;
  if (e >= E) return;
  int s = src[e], d = dst[e];
  int pos = atomicAdd(&cursor[d], 1);
  es[pos] = s;
  wn[pos] = dis[s] * ew[e] * dis[d];
}

// ---- pull aggregation: xo[n] = bias + dis[n]^2*xw[n] + sum_j wn[j]*xw[es[j]] ----
__global__ __launch_bounds__(128) void k_agg(const float* __restrict__ xw,
        const int* __restrict__ row_start, const int* __restrict__ es,
        const float* __restrict__ wn, const float* __restrict__ dis,
        const float* __restrict__ bias, float* __restrict__ xo, int N){
  int n = blockIdx.x, d = threadIdx.x;
  float dv = dis[n];
  float acc = bias[d] + xw[(size_t)n*Dc + d]*dv*dv;
  int j = row_start[n], j1 = row_start[n+1];
  for (; j + 1 < j1; j += 2){
    int   s0 = es[j],  s1 = es[j+1];
    float w0 = wn[j],  w1 = wn[j+1];
    acc += xw[(size_t)s0*Dc + d]*w0 + xw[(size_t)s1*Dc + d]*w1;
  }
  if (j < j1) acc += xw[(size_t)es[j]*Dc + d]*wn[j];
  xo[(size_t)n*Dc + d] = acc;
}

// ==== image GEMM v2: partials, no atomics ====
// block: 512 threads = 256 col-pairs x 2 K-subsegments; grid (IMG/512, nseg/2).
// P[segi*BI + b*IMG + col] = sum_{k in seg} images[b,k] * W[k,col]
__global__ __launch_bounds__(512) void k_img_mm(const float* __restrict__ images,
        const float* __restrict__ Wimg, float* __restrict__ P,
        int IMG, int KSEG){
  int tcol = threadIdx.x & 255;
  int sub  = threadIdx.x >> 8;
  int col  = blockIdx.x*512 + tcol*2;
  int segi = blockIdx.y*2 + sub;
  int k0   = segi * KSEG;
  float2 acc[NG];
  #pragma unroll
  for (int b = 0; b < NG; b++){ acc[b].x = 0.f; acc[b].y = 0.f; }
  const float* wp = Wimg + (size_t)k0*IMG + col;
  for (int k = 0; k < KSEG; k++){
    float2 w = *(const float2*)wp;
    wp += IMG;
    const float* ip = images + (size_t)k0 + k;   // uniform per b -> scalar loads
    #pragma unroll
    for (int b = 0; b < NG; b++){
      float iv = ip[(size_t)b*IMG];
      acc[b].x += iv*w.x; acc[b].y += iv*w.y;
    }
  }
  size_t base = (size_t)segi*NG*IMG + col;
  #pragma unroll
  for (int b = 0; b < NG; b++)
    *(float2*)&P[base + (size_t)b*IMG] = acc[b];
}

// ---- q[i] += sum_seg P[seg*BI + i]  (q pre-initialized to bias) ----
__global__ __launch_bounds__(256) void k_img_reduce(const float* __restrict__ P,
        float* __restrict__ q, int BI, int nseg){
  int i = blockIdx.x*256 + threadIdx.x;
  if (i >= BI) return;
  float s = q[i];
  for (int g = 0; g < nseg; g++) s += P[(size_t)g*BI + i];
  q[i] = s;
}

// ---- legacy image GEMM (fallback when IMG%512 != 0): split-K + LDS staging ----
constexpr int KCH = 32;
__global__ __launch_bounds__(256) void k_img_mm_legacy(const float* __restrict__ images,
        const float* __restrict__ Wimg, float* __restrict__ q, int IMG, int KSEG){
  __shared__ float Ls[KCH][NG];
  int col = blockIdx.x*256 + threadIdx.x;
  int k0  = blockIdx.y * KSEG;
  float acc[NG];
  #pragma unroll
  for (int b = 0; b < NG; b++) acc[b] = 0.f;
  for (int kk = k0; kk < k0 + KSEG; kk += KCH){
    int t = threadIdx.x;
    for (int i = t; i < KCH*NG; i += 256){
      int b = i & (NG-1), k = i >> 5;
      Ls[k][b] = images[(size_t)b*IMG + kk + k];
    }
    __syncthreads();
    for (int k = 0; k < KCH; k++){
      float w = Wimg[(size_t)(kk+k)*IMG + col];
      #pragma unroll
      for (int b = 0; b < NG; b++) acc[b] += Ls[k][b] * w;
    }
    __syncthreads();
  }
  for (int b = 0; b < NG; b++) atomicAdd(&q[(size_t)b*IMG + col], acc[b]);
}

// ---- image head, split-K: qi[b,d] += sum_{k in seg} q[b,k] * Wi[k,d] ----
constexpr int IKS = 16;   // K segments
__global__ __launch_bounds__(128) void k_ihead_mm(const float* __restrict__ q,
        const float* __restrict__ Wi, float* __restrict__ qi, int IMG){
  int b = blockIdx.x, seg = blockIdx.y, d = threadIdx.x;
  int kseg = IMG / IKS;
  const float* qr = q  + (size_t)b*IMG + (size_t)seg*kseg;
  const float* wr = Wi + (size_t)seg*kseg*Dc + d;
  float acc = 0.f;
  for (int k = 0; k < kseg; k++) acc += qr[k] * wr[(size_t)k*Dc];  // qr uniform, wr coalesced
  atomicAdd(&qi[b*Dc + d], acc);
}

// ---- out_images = l2norm(qi) ----
__global__ __launch_bounds__(128) void k_ihead_norm(const float* __restrict__ qi,
        float* __restrict__ out){
  int b = blockIdx.x, d = threadIdx.x;
  float v = qi[b*Dc + d];
  __shared__ float red[Dc];
  red[d] = v*v; __syncthreads();
  for (int s = Dc/2; s > 0; s >>= 1){ if (d < s) red[d] += red[d+s]; __syncthreads(); }
  out[b*Dc + d] = v * rsqrtf(red[0]);
}

// ---- xw = (relu?)x @ W   (W staged in LDS fp32; float4 x loads) ----
__global__ __launch_bounds__(256) void k_mm(const float* __restrict__ x,
        const float* __restrict__ W, float* __restrict__ xw, int N, int relu){
  __shared__ float Ws[Dc*Dc];
  int t = threadIdx.x;
  for (int i = t; i < Dc*Dc; i += 256) Ws[i] = W[i];
  __syncthreads();
  int r = t >> 5, c4 = (t & 31) << 2;
  int n = blockIdx.x*8 + r;
  if (n >= N) return;
  const float* xr = x + (size_t)n*Dc;
  float a0=0,a1=0,a2=0,a3=0;
  for (int k = 0; k < Dc; k += 4){
    float4 xv = *(const float4*)&xr[k];
    if (relu){
      xv.x = fmaxf(xv.x, 0.f); xv.y = fmaxf(xv.y, 0.f);
      xv.z = fmaxf(xv.z, 0.f); xv.w = fmaxf(xv.w, 0.f);
    }
    const float4 w0 = *(const float4*)&Ws[(k+0)*Dc + c4];
    const float4 w1 = *(const float4*)&Ws[(k+1)*Dc + c4];
    const float4 w2 = *(const float4*)&Ws[(k+2)*Dc + c4];
    const float4 w3 = *(const float4*)&Ws[(k+3)*Dc + c4];
    a0 += xv.x*w0.x + xv.y*w1.x + xv.z*w2.x + xv.w*w3.x;
    a1 += xv.x*w0.y + xv.y*w1.y + xv.z*w2.y + xv.w*w3.y;
    a2 += xv.x*w0.z + xv.y*w1.z + xv.z*w2.z + xv.w*w3.z;
    a3 += xv.x*w0.w + xv.y*w1.w + xv.z*w2.w + xv.w*w3.w;
  }
  float4 o = {a0,a1,a2,a3};
  *(float4*)&xw[(size_t)n*Dc + c4] = o;
}

// ---- mean pool by graph (batch sorted); flush only block's graph range ----
__global__ __launch_bounds__(128) void k_pool(const float* __restrict__ x,
        const int* __restrict__ batch, float* __restrict__ pooled,
        float* __restrict__ cnt, int N){
  __shared__ float acc[NG*Dc];
  __shared__ float cl[NG];
  int t = threadIdx.x;
  int chunk = (N + gridDim.x - 1) / gridDim.x;
  int s = blockIdx.x*chunk;
  int e = min(N, s + chunk);
  if (s >= e) return;                 // whole block exits together
  for (int i = t; i < NG*Dc; i += 128) acc[i] = 0.f;
  if (t < NG) cl[t] = 0.f;
  __syncthreads();
  for (int n = s; n < e; n++){
    int g = batch[n];
    acc[g*Dc + t] += x[(size_t)n*Dc + t];
    if (t == 0) cl[g] += 1.f;
  }
  __syncthreads();
  int gmin = batch[s], gmax = batch[e-1];
  for (int g = gmin; g <= gmax; g++) atomicAdd(&pooled[g*Dc + t], acc[g*Dc + t]);
  if (t >= gmin && t <= gmax) atomicAdd(&cnt[t], cl[t]);
}

// ---- out_graphs = l2norm((pooled/cnt) @ W_g + b_g) ----
__global__ __launch_bounds__(128) void k_head(const float* __restrict__ pooled,
        const float* __restrict__ cnt, const float* __restrict__ Wg,
        const float* __restrict__ bg, float* __restrict__ outg){
  int g = blockIdx.x, t = threadIdx.x;
  __shared__ float m[Dc];
  __shared__ float red[Dc];
  float c = fmaxf(cnt[g], 1.f);
  m[t] = pooled[g*Dc + t] / c;
  __syncthreads();
  float acc = bg[t];
  for (int k = 0; k < Dc; k++) acc += m[k] * Wg[k*Dc + t];
  red[t] = acc*acc; __syncthreads();
  for (int s = Dc/2; s > 0; s >>= 1){ if (t < s) red[t] += red[t+s]; __syncthreads(); }
  outg[g*Dc + t] = acc * rsqrtf(red[0]);
}

extern "C" void kernel_launch(void* const* d_in, const int* in_sizes, int n_in,
                              void* d_out, int out_size, void* d_ws, size_t ws_size,
                              hipStream_t stream){
  float* out = (float*)d_out;   // reference outputs are float32

  // ---- dict-order signature verification; absmax ~= 700+code names first bad slot ----
  int fail = 0;
  auto chk = [&](bool ok, int code){ if (!fail && !ok) fail = code; };
  chk(n_in == 19, 1);
  int IMG = 0, N = 0, E = 0;
  if (!fail){
    IMG = in_sizes[0] / NG;                     // images = [NG, IMG]
    N   = in_sizes[1];                          // node_ids
    E   = in_sizes[2];                          // src
    chk(IMG >= 256 && (IMG % 256) == 0 && in_sizes[0] == NG*IMG, 2);
    chk(in_sizes[3] == E && in_sizes[4] == E, 3);        // dst, edge_attr
    chk(in_sizes[5] == N, 4);                            // batch
    chk(in_sizes[6] > 0 && (in_sizes[6] % Dc) == 0, 5);  // node_emb [VOCAB, 128]
    chk((long long)in_sizes[7] == (long long)IMG*IMG, 6);// W_img
    chk(in_sizes[8] == IMG, 7);                          // b_img
    chk((long long)in_sizes[9] == (long long)IMG*Dc, 8); // W_i
    chk(in_sizes[10] == Dc, 9);                          // b_i
    chk(in_sizes[11] == Dc*Dc && in_sizes[13] == Dc*Dc &&
        in_sizes[15] == Dc*Dc && in_sizes[17] == Dc*Dc, 10); // W1..W3, W_g
    chk(in_sizes[12] == Dc && in_sizes[14] == Dc &&
        in_sizes[16] == Dc && in_sizes[18] == Dc, 11);       // b1..b3, b_g
    chk(out_size == 2*NG*Dc, 12);
  }
  if (fail){
    k_sentinel<<<(out_size+255)/256, 256, 0, stream>>>(out, 700.f + (float)fail, out_size);
    return;
  }

  const float* images   = (const float*)d_in[0];
  const int*   node_ids = (const int*)  d_in[1];
  const int*   src      = (const int*)  d_in[2];
  const int*   dst      = (const int*)  d_in[3];
  const float* eattr    = (const float*)d_in[4];
  const int*   batch    = (const int*)  d_in[5];
  const float* emb      = (const float*)d_in[6];
  const float* W_img    = (const float*)d_in[7];
  const float* b_img    = (const float*)d_in[8];
  const float* W_i      = (const float*)d_in[9];
  const float* b_i      = (const float*)d_in[10];
  const float* W1       = (const float*)d_in[11];
  const float* b1       = (const float*)d_in[12];
  const float* W2       = (const float*)d_in[13];
  const float* b2       = (const float*)d_in[14];
  const float* W3       = (const float*)d_in[15];
  const float* b3       = (const float*)d_in[16];
  const float* W_g      = (const float*)d_in[17];
  const float* b_g      = (const float*)d_in[18];

  const int BI = NG * IMG;
  const int ND = N * Dc;
  const int nb = (N + 255) / 256;     // scan blocks

  // ---- workspace layout: common fp32 region, then CSR int region ----
  size_t common = 2*(size_t)ND + E + N + BI + NG*Dc + NG + NG*Dc;   // floats
  size_t csr_i  = (size_t)E + (N+1) + N + N + 256;                   // ints
  size_t need   = common*sizeof(float) + csr_i*sizeof(int);
  if (ws_size < need || nb > 256){
    k_sentinel<<<(out_size+255)/256, 256, 0, stream>>>(out, 690.f, out_size);
    return;
  }

  float* ws    = (float*)d_ws;
  float* xA    = ws;  ws += (size_t)ND;
  float* xw    = ws;  ws += (size_t)ND;
  float* wn    = ws;  ws += E;          // CSR weights
  float* dis   = ws;  ws += N;          // holds deg first, then rsqrt in place
  float* q     = ws;  ws += BI;
  float* pooled= ws;  ws += NG*Dc;
  float* cnt   = ws;  ws += NG;
  float* qi    = ws;  ws += NG*Dc;
  int* iw        = (int*)ws;
  int* es        = iw;  iw += E;        // CSR src indices
  int* row_start = iw;  iw += N+1;
  int* cursor    = iw;  iw += N;
  int* cntN      = iw;  iw += N;
  int* bsum      = iw;  iw += 256;

  float* P = xA;   // image-GEMM partials live in [xA, xA+2*ND+E) BEFORE graph path

  k_init<<<(BI+255)/256, 256, 0, stream>>>(b_img, q, dis, pooled, b_i, qi, cntN, BI, IMG, N);

  // ---- image path first (partials reuse the xA/xw/wn region) ----
  int nseg = 64;
  while (nseg > 4 && (size_t)nseg*BI > 2*(size_t)ND + E) nseg >>= 1;
  bool v2 = ((IMG % 512) == 0) && ((size_t)nseg*BI <= 2*(size_t)ND + E);
  if (v2){
    k_img_mm    <<<dim3(IMG/512, nseg/2), 512, 0, stream>>>(images, W_img, P, IMG, IMG/nseg);
    k_img_reduce<<<(BI+255)/256, 256, 0, stream>>>(P, q, BI, nseg);
  } else {
    const int KSPLIT = ((IMG % (16*KCH)) == 0) ? 16 : 8;
    k_img_mm_legacy<<<dim3(IMG/256, KSPLIT), 256, 0, stream>>>(images, W_img, q, IMG, IMG/KSPLIT);
  }
  k_ihead_mm  <<<dim3(NG, IKS), Dc, 0, stream>>>(q, W_i, qi, IMG);
  k_ihead_norm<<<NG, Dc, 0, stream>>>(qi, out);

  // ---- graph path ----
  k_gather<<<(ND+255)/256, 256, 0, stream>>>(emb, node_ids, xA, ND);
  k_deg2  <<<(E+255)/256, 256, 0, stream>>>(dst, eattr, dis, cntN, E);
  k_dis   <<<(N+255)/256, 256, 0, stream>>>(dis, N);
  k_scan_partial<<<nb, 256, 0, stream>>>(cntN, bsum, N);
  k_scan_bsum   <<<1,  256, 0, stream>>>(bsum, nb, row_start, N, E);
  k_scan_final  <<<nb, 256, 0, stream>>>(cntN, bsum, row_start, cursor, N);
  k_fill        <<<(E+255)/256, 256, 0, stream>>>(src, dst, eattr, dis, cursor, es, wn, E);

  const float* Wl[3] = {W1, W2, W3};
  const float* bl[3] = {b1, b2, b3};
  for (int l = 0; l < 3; l++){
    k_mm <<<(N+7)/8, 256, 0, stream>>>(xA, Wl[l], xw, N, l > 0);
    k_agg<<<N, Dc, 0, stream>>>(xw, row_start, es, wn, dis, bl[l], xA, N);
  }

  k_pool<<<256, Dc, 0, stream>>>(xA, batch, pooled, cnt, N);
  k_head<<<NG, Dc, 0, stream>>>(pooled, cnt, W_g, b_g, out + NG*Dc);
}

// Round 10
// 997.462 us; speedup vs baseline: 1.7212x; 1.7212x over previous
//
#include <hip/hip_runtime.h>
#include <hip/hip_bf16.h>

constexpr int Dc = 128;   // feature dim
constexpr int NG = 32;    // num graphs / batch size

// ---- sentinel: encode a diagnostic code in the output magnitude ----
__global__ void k_sentinel(float* __restrict__ out, float val, int n){
  int i = blockIdx.x*256 + threadIdx.x;
  if (i < n) out[i] = val;
}

// ---- init: q = b_img, deg = 1.0 (self-loop weight), pooled/cnt = 0, qi = b_i, cntN = 0 ----
__global__ void k_init(const float* __restrict__ b_img, float* __restrict__ q,
                       float* __restrict__ deg, float* __restrict__ pooled,
                       const float* __restrict__ b_i, float* __restrict__ qi,
                       int* __restrict__ cntN, int BI, int IMG, int N){
  int i = blockIdx.x*256 + threadIdx.x;
  if (i < BI) q[i] = b_img[i % IMG];
  if (i < N){ deg[i] = 1.0f; cntN[i] = 0; }
  if (i < NG*Dc + NG) pooled[i] = 0.f;   // pooled followed by cnt
  if (i < NG*Dc) qi[i] = b_i[i & (Dc-1)];
}

// ---- x0 = node_emb[node_ids] ----
__global__ void k_gather(const float* __restrict__ emb, const int* __restrict__ ids,
                         float* __restrict__ x, int ND){
  int i = blockIdx.x*256 + threadIdx.x;
  if (i >= ND) return;
  int n = i >> 7, d = i & (Dc-1);
  x[i] = emb[(size_t)ids[n]*Dc + d];
}

// ---- deg[dst] += ew ; count in-edges per node ----
__global__ void k_deg2(const int* __restrict__ dst, const float* __restrict__ ew,
                       float* __restrict__ deg, int* __restrict__ cntN, int E){
  int e = blockIdx.x*256 + threadIdx.x;
  if (e >= E) return;
  int d = dst[e];
  atomicAdd(&deg[d], ew[e]);
  atomicAdd(&cntN[d], 1);
}

// ---- dis = rsqrt(deg) in place (deg >= 1 due to self-loops) ----
__global__ void k_dis(float* __restrict__ deg, int N){
  int i = blockIdx.x*256 + threadIdx.x;
  if (i < N) deg[i] = rsqrtf(deg[i]);
}

// ==== CSR build: 3-kernel exclusive scan over cntN, then fill ====
__global__ __launch_bounds__(256) void k_scan_partial(const int* __restrict__ cnt,
        int* __restrict__ bsum, int N){
  __shared__ int red[256];
  int t = threadIdx.x, i = blockIdx.x*256 + t;
  red[t] = (i < N) ? cnt[i] : 0;
  __syncthreads();
  for (int s = 128; s > 0; s >>= 1){ if (t < s) red[t] += red[t+s]; __syncthreads(); }
  if (t == 0) bsum[blockIdx.x] = red[0];
}

__global__ __launch_bounds__(256) void k_scan_bsum(int* __restrict__ bsum, int nb,
        int* __restrict__ row_start, int N, int E){
  __shared__ int sc[256];
  int t = threadIdx.x;
  int orig = (t < nb) ? bsum[t] : 0;
  sc[t] = orig;
  __syncthreads();
  for (int off = 1; off < 256; off <<= 1){
    int v = (t >= off) ? sc[t-off] : 0;
    __syncthreads();
    sc[t] += v;
    __syncthreads();
  }
  if (t < nb) bsum[t] = sc[t] - orig;   // exclusive
  if (t == 0) row_start[N] = E;
}

__global__ __launch_bounds__(256) void k_scan_final(const int* __restrict__ cnt,
        const int* __restrict__ bsum, int* __restrict__ row_start,
        int* __restrict__ cursor, int N){
  __shared__ int sc[256];
  int t = threadIdx.x, i = blockIdx.x*256 + t;
  int orig = (i < N) ? cnt[i] : 0;
  sc[t] = orig;
  __syncthreads();
  for (int off = 1; off < 256; off <<= 1){
    int v = (t >= off) ? sc[t-off] : 0;
    __syncthreads();
    sc[t] += v;
    __syncthreads();
  }
  if (i < N){
    int ex = bsum[blockIdx.x] + sc[t] - orig;
    row_start[i] = ex;
    cursor[i]    = ex;
  }
}

// ---- fill CSR: es[pos]=src, wn[pos]=dis[src]*ew*dis[dst] ----
__global__ void k_fill(const int* __restrict__ src, const int* __restrict__ dst,
        const float* __restrict__ ew, const float* __restrict__ dis,
        int* __restrict__ cursor, int* __restrict__ es, float* __restrict__ wn, int E){
  int e = blockIdx.x*256 + threadIdx.x;
  if (e >= E) return;
  int s = src[e], d = dst[e];
  int pos = atomicAdd(&cursor[d], 1);
  es[pos] = s;
  wn[pos] = dis[s] * ew[e] * dis[d];
}

// ---- pull aggregation: xo[n] = bias + dis[n]^2*xw[n] + sum_j wn[j]*xw[es[j]] ----
__global__ __launch_bounds__(128) void k_agg(const float* __restrict__ xw,
        const int* __restrict__ row_start, const int* __restrict__ es,
        const float* __restrict__ wn, const float* __restrict__ dis,
        const float* __restrict__ bias, float* __restrict__ xo, int N){
  int n = blockIdx.x, d = threadIdx.x;
  float dv = dis[n];
  float acc = bias[d] + xw[(size_t)n*Dc + d]*dv*dv;
  int j = row_start[n], j1 = row_start[n+1];
  for (; j + 1 < j1; j += 2){
    int   s0 = es[j],  s1 = es[j+1];
    float w0 = wn[j],  w1 = wn[j+1];
    acc += xw[(size_t)s0*Dc + d]*w0 + xw[(size_t)s1*Dc + d]*w1;
  }
  if (j < j1) acc += xw[(size_t)es[j]*Dc + d]*wn[j];
  xo[(size_t)n*Dc + d] = acc;
}

// ==== image GEMM v2: partials, no atomics ====
// block: 512 threads = 256 col-pairs x 2 K-subsegments; grid (IMG/512, nseg/2).
// P[segi*BI + b*IMG + col] = sum_{k in seg} images[b,k] * W[k,col]
__global__ __launch_bounds__(512) void k_img_mm(const float* __restrict__ images,
        const float* __restrict__ Wimg, float* __restrict__ P,
        int IMG, int KSEG){
  int tcol = threadIdx.x & 255;
  int sub  = threadIdx.x >> 8;
  int col  = blockIdx.x*512 + tcol*2;
  int segi = blockIdx.y*2 + sub;
  int k0   = segi * KSEG;
  float2 acc[NG];
  #pragma unroll
  for (int b = 0; b < NG; b++){ acc[b].x = 0.f; acc[b].y = 0.f; }
  const float* wp = Wimg + (size_t)k0*IMG + col;
  for (int k = 0; k < KSEG; k++){
    float2 w = *(const float2*)wp;
    wp += IMG;
    const float* ip = images + (size_t)k0 + k;   // uniform per b -> scalar loads
    #pragma unroll
    for (int b = 0; b < NG; b++){
      float iv = ip[(size_t)b*IMG];
      acc[b].x += iv*w.x; acc[b].y += iv*w.y;
    }
  }
  size_t base = (size_t)segi*NG*IMG + col;
  #pragma unroll
  for (int b = 0; b < NG; b++)
    *(float2*)&P[base + (size_t)b*IMG] = acc[b];
}

// ---- q[i] += sum_seg P[seg*BI + i]  (q pre-initialized to bias) ----
__global__ __launch_bounds__(256) void k_img_reduce(const float* __restrict__ P,
        float* __restrict__ q, int BI, int nseg){
  int i = blockIdx.x*256 + threadIdx.x;
  if (i >= BI) return;
  float s = q[i];
  for (int g = 0; g < nseg; g++) s += P[(size_t)g*BI + i];
  q[i] = s;
}

// ---- legacy image GEMM (fallback when IMG%512 != 0): split-K + LDS staging ----
constexpr int KCH = 32;
__global__ __launch_bounds__(256) void k_img_mm_legacy(const float* __restrict__ images,
        const float* __restrict__ Wimg, float* __restrict__ q, int IMG, int KSEG){
  __shared__ float Ls[KCH][NG];
  int col = blockIdx.x*256 + threadIdx.x;
  int k0  = blockIdx.y * KSEG;
  float acc[NG];
  #pragma unroll
  for (int b = 0; b < NG; b++) acc[b] = 0.f;
  for (int kk = k0; kk < k0 + KSEG; kk += KCH){
    int t = threadIdx.x;
    for (int i = t; i < KCH*NG; i += 256){
      int b = i & (NG-1), k = i >> 5;
      Ls[k][b] = images[(size_t)b*IMG + kk + k];
    }
    __syncthreads();
    for (int k = 0; k < KCH; k++){
      float w = Wimg[(size_t)(kk+k)*IMG + col];
      #pragma unroll
      for (int b = 0; b < NG; b++) acc[b] += Ls[k][b] * w;
    }
    __syncthreads();
  }
  for (int b = 0; b < NG; b++) atomicAdd(&q[(size_t)b*IMG + col], acc[b]);
}

// ---- image head, split-K: qi[b,d] += sum_{k in seg} q[b,k] * Wi[k,d] ----
constexpr int IKS = 16;   // K segments
__global__ __launch_bounds__(128) void k_ihead_mm(const float* __restrict__ q,
        const float* __restrict__ Wi, float* __restrict__ qi, int IMG){
  int b = blockIdx.x, seg = blockIdx.y, d = threadIdx.x;
  int kseg = IMG / IKS;
  const float* qr = q  + (size_t)b*IMG + (size_t)seg*kseg;
  const float* wr = Wi + (size_t)seg*kseg*Dc + d;
  float acc = 0.f;
  for (int k = 0; k < kseg; k++) acc += qr[k] * wr[(size_t)k*Dc];  // qr uniform, wr coalesced
  atomicAdd(&qi[b*Dc + d], acc);
}

// ---- out_images = l2norm(qi) ----
__global__ __launch_bounds__(128) void k_ihead_norm(const float* __restrict__ qi,
        float* __restrict__ out){
  int b = blockIdx.x, d = threadIdx.x;
  float v = qi[b*Dc + d];
  __shared__ float red[Dc];
  red[d] = v*v; __syncthreads();
  for (int s = Dc/2; s > 0; s >>= 1){ if (d < s) red[d] += red[d+s]; __syncthreads(); }
  out[b*Dc + d] = v * rsqrtf(red[0]);
}

// ---- xw = (relu?)x @ W  (R8-proven body: scalar x loads, float4 LDS weight reads)
// NOTE: R9's float4-x + manual 4x unroll variant spilled (VGPR 256, 620 MB
// scratch writes/dispatch, 320-390 us). Keep this version.
__global__ __launch_bounds__(256) void k_mm(const float* __restrict__ x,
        const float* __restrict__ W, float* __restrict__ xw, int N, int relu){
  __shared__ float Ws[Dc*Dc];
  int t = threadIdx.x;
  for (int i = t; i < Dc*Dc; i += 256) Ws[i] = W[i];
  __syncthreads();
  int r = t >> 5, c4 = (t & 31) << 2;
  int n = blockIdx.x*8 + r;
  if (n >= N) return;
  const float* xr = x + (size_t)n*Dc;
  float a0=0,a1=0,a2=0,a3=0;
  for (int k = 0; k < Dc; k++){
    float xv = xr[k];
    if (relu) xv = fmaxf(xv, 0.f);
    const float4 w = *(const float4*)&Ws[k*Dc + c4];
    a0 += xv*w.x; a1 += xv*w.y; a2 += xv*w.z; a3 += xv*w.w;
  }
  float4 o = {a0,a1,a2,a3};
  *(float4*)&xw[(size_t)n*Dc + c4] = o;
}

// ---- mean pool by graph (batch sorted); flush only block's graph range ----
__global__ __launch_bounds__(128) void k_pool(const float* __restrict__ x,
        const int* __restrict__ batch, float* __restrict__ pooled,
        float* __restrict__ cnt, int N){
  __shared__ float acc[NG*Dc];
  __shared__ float cl[NG];
  int t = threadIdx.x;
  int chunk = (N + gridDim.x - 1) / gridDim.x;
  int s = blockIdx.x*chunk;
  int e = min(N, s + chunk);
  if (s >= e) return;                 // whole block exits together
  for (int i = t; i < NG*Dc; i += 128) acc[i] = 0.f;
  if (t < NG) cl[t] = 0.f;
  __syncthreads();
  for (int n = s; n < e; n++){
    int g = batch[n];
    acc[g*Dc + t] += x[(size_t)n*Dc + t];
    if (t == 0) cl[g] += 1.f;
  }
  __syncthreads();
  int gmin = batch[s], gmax = batch[e-1];
  for (int g = gmin; g <= gmax; g++) atomicAdd(&pooled[g*Dc + t], acc[g*Dc + t]);
  if (t >= gmin && t <= gmax) atomicAdd(&cnt[t], cl[t]);
}

// ---- out_graphs = l2norm((pooled/cnt) @ W_g + b_g) ----
__global__ __launch_bounds__(128) void k_head(const float* __restrict__ pooled,
        const float* __restrict__ cnt, const float* __restrict__ Wg,
        const float* __restrict__ bg, float* __restrict__ outg){
  int g = blockIdx.x, t = threadIdx.x;
  __shared__ float m[Dc];
  __shared__ float red[Dc];
  float c = fmaxf(cnt[g], 1.f);
  m[t] = pooled[g*Dc + t] / c;
  __syncthreads();
  float acc = bg[t];
  for (int k = 0; k < Dc; k++) acc += m[k] * Wg[k*Dc + t];
  red[t] = acc*acc; __syncthreads();
  for (int s = Dc/2; s > 0; s >>= 1){ if (t < s) red[t] += red[t+s]; __syncthreads(); }
  outg[g*Dc + t] = acc * rsqrtf(red[0]);
}

extern "C" void kernel_launch(void* const* d_in, const int* in_sizes, int n_in,
                              void* d_out, int out_size, void* d_ws, size_t ws_size,
                              hipStream_t stream){
  float* out = (float*)d_out;   // reference outputs are float32

  // ---- dict-order signature verification; absmax ~= 700+code names first bad slot ----
  int fail = 0;
  auto chk = [&](bool ok, int code){ if (!fail && !ok) fail = code; };
  chk(n_in == 19, 1);
  int IMG = 0, N = 0, E = 0;
  if (!fail){
    IMG = in_sizes[0] / NG;                     // images = [NG, IMG]
    N   = in_sizes[1];                          // node_ids
    E   = in_sizes[2];                          // src
    chk(IMG >= 256 && (IMG % 256) == 0 && in_sizes[0] == NG*IMG, 2);
    chk(in_sizes[3] == E && in_sizes[4] == E, 3);        // dst, edge_attr
    chk(in_sizes[5] == N, 4);                            // batch
    chk(in_sizes[6] > 0 && (in_sizes[6] % Dc) == 0, 5);  // node_emb [VOCAB, 128]
    chk((long long)in_sizes[7] == (long long)IMG*IMG, 6);// W_img
    chk(in_sizes[8] == IMG, 7);                          // b_img
    chk((long long)in_sizes[9] == (long long)IMG*Dc, 8); // W_i
    chk(in_sizes[10] == Dc, 9);                          // b_i
    chk(in_sizes[11] == Dc*Dc && in_sizes[13] == Dc*Dc &&
        in_sizes[15] == Dc*Dc && in_sizes[17] == Dc*Dc, 10); // W1..W3, W_g
    chk(in_sizes[12] == Dc && in_sizes[14] == Dc &&
        in_sizes[16] == Dc && in_sizes[18] == Dc, 11);       // b1..b3, b_g
    chk(out_size == 2*NG*Dc, 12);
  }
  if (fail){
    k_sentinel<<<(out_size+255)/256, 256, 0, stream>>>(out, 700.f + (float)fail, out_size);
    return;
  }

  const float* images   = (const float*)d_in[0];
  const int*   node_ids = (const int*)  d_in[1];
  const int*   src      = (const int*)  d_in[2];
  const int*   dst      = (const int*)  d_in[3];
  const float* eattr    = (const float*)d_in[4];
  const int*   batch    = (const int*)  d_in[5];
  const float* emb      = (const float*)d_in[6];
  const float* W_img    = (const float*)d_in[7];
  const float* b_img    = (const float*)d_in[8];
  const float* W_i      = (const float*)d_in[9];
  const float* b_i      = (const float*)d_in[10];
  const float* W1       = (const float*)d_in[11];
  const float* b1       = (const float*)d_in[12];
  const float* W2       = (const float*)d_in[13];
  const float* b2       = (const float*)d_in[14];
  const float* W3       = (const float*)d_in[15];
  const float* b3       = (const float*)d_in[16];
  const float* W_g      = (const float*)d_in[17];
  const float* b_g      = (const float*)d_in[18];

  const int BI = NG * IMG;
  const int ND = N * Dc;
  const int nb = (N + 255) / 256;     // scan blocks

  // ---- workspace layout: common fp32 region, then CSR int region ----
  size_t common = 2*(size_t)ND + E + N + BI + NG*Dc + NG + NG*Dc;   // floats
  size_t csr_i  = (size_t)E + (N+1) + N + N + 256;                   // ints
  size_t need   = common*sizeof(float) + csr_i*sizeof(int);
  if (ws_size < need || nb > 256){
    k_sentinel<<<(out_size+255)/256, 256, 0, stream>>>(out, 690.f, out_size);
    return;
  }

  float* ws    = (float*)d_ws;
  float* xA    = ws;  ws += (size_t)ND;
  float* xw    = ws;  ws += (size_t)ND;
  float* wn    = ws;  ws += E;          // CSR weights
  float* dis   = ws;  ws += N;          // holds deg first, then rsqrt in place
  float* q     = ws;  ws += BI;
  float* pooled= ws;  ws += NG*Dc;
  float* cnt   = ws;  ws += NG;
  float* qi    = ws;  ws += NG*Dc;
  int* iw        = (int*)ws;
  int* es        = iw;  iw += E;        // CSR src indices
  int* row_start = iw;  iw += N+1;
  int* cursor    = iw;  iw += N;
  int* cntN      = iw;  iw += N;
  int* bsum      = iw;  iw += 256;

  float* P = xA;   // image-GEMM partials live in [xA, xA+2*ND+E) BEFORE graph path

  k_init<<<(BI+255)/256, 256, 0, stream>>>(b_img, q, dis, pooled, b_i, qi, cntN, BI, IMG, N);

  // ---- image path first (partials reuse the xA/xw/wn region) ----
  int nseg = 64;
  while (nseg > 4 && (size_t)nseg*BI > 2*(size_t)ND + E) nseg >>= 1;
  bool v2 = ((IMG % 512) == 0) && ((size_t)nseg*BI <= 2*(size_t)ND + E);
  if (v2){
    k_img_mm    <<<dim3(IMG/512, nseg/2), 512, 0, stream>>>(images, W_img, P, IMG, IMG/nseg);
    k_img_reduce<<<(BI+255)/256, 256, 0, stream>>>(P, q, BI, nseg);
  } else {
    const int KSPLIT = ((IMG % (16*KCH)) == 0) ? 16 : 8;
    k_img_mm_legacy<<<dim3(IMG/256, KSPLIT), 256, 0, stream>>>(images, W_img, q, IMG, IMG/KSPLIT);
  }
  k_ihead_mm  <<<dim3(NG, IKS), Dc, 0, stream>>>(q, W_i, qi, IMG);
  k_ihead_norm<<<NG, Dc, 0, stream>>>(qi, out);

  // ---- graph path ----
  k_gather<<<(ND+255)/256, 256, 0, stream>>>(emb, node_ids, xA, ND);
  k_deg2  <<<(E+255)/256, 256, 0, stream>>>(dst, eattr, dis, cntN, E);
  k_dis   <<<(N+255)/256, 256, 0, stream>>>(dis, N);
  k_scan_partial<<<nb, 256, 0, stream>>>(cntN, bsum, N);
  k_scan_bsum   <<<1,  256, 0, stream>>>(bsum, nb, row_start, N, E);
  k_scan_final  <<<nb, 256, 0, stream>>>(cntN, bsum, row_start, cursor, N);
  k_fill        <<<(E+255)/256, 256, 0, stream>>>(src, dst, eattr, dis, cursor, es, wn, E);

  const float* Wl[3] = {W1, W2, W3};
  const float* bl[3] = {b1, b2, b3};
  for (int l = 0; l < 3; l++){
    k_mm <<<(N+7)/8, 256, 0, stream>>>(xA, Wl[l], xw, N, l > 0);
    k_agg<<<N, Dc, 0, stream>>>(xw, row_start, es, wn, dis, bl[l], xA, N);
  }

  k_pool<<<256, Dc, 0, stream>>>(xA, batch, pooled, cnt, N);
  k_head<<<NG, Dc, 0, stream>>>(pooled, cnt, W_g, b_g, out + NG*Dc);
}

// Round 11
// 760.262 us; speedup vs baseline: 2.2582x; 1.3120x over previous
//
#include <hip/hip_runtime.h>
#include <hip/hip_bf16.h>

constexpr int Dc = 128;   // feature dim
constexpr int NG = 32;    // num graphs / batch size

// ---- sentinel: encode a diagnostic code in the output magnitude ----
__global__ void k_sentinel(float* __restrict__ out, float val, int n){
  int i = blockIdx.x*256 + threadIdx.x;
  if (i < n) out[i] = val;
}

// ---- init: q = b_img, deg = 1.0 (self-loop weight), pooled/cnt = 0, qi = b_i, cntN = 0 ----
__global__ void k_init(const float* __restrict__ b_img, float* __restrict__ q,
                       float* __restrict__ deg, float* __restrict__ pooled,
                       const float* __restrict__ b_i, float* __restrict__ qi,
                       int* __restrict__ cntN, int BI, int IMG, int N){
  int i = blockIdx.x*256 + threadIdx.x;
  if (i < BI) q[i] = b_img[i % IMG];
  if (i < N){ deg[i] = 1.0f; cntN[i] = 0; }
  if (i < NG*Dc + NG) pooled[i] = 0.f;   // pooled followed by cnt
  if (i < NG*Dc) qi[i] = b_i[i & (Dc-1)];
}

// ---- x0 = node_emb[node_ids] ----
__global__ void k_gather(const float* __restrict__ emb, const int* __restrict__ ids,
                         float* __restrict__ x, int ND){
  int i = blockIdx.x*256 + threadIdx.x;
  if (i >= ND) return;
  int n = i >> 7, d = i & (Dc-1);
  x[i] = emb[(size_t)ids[n]*Dc + d];
}

// ---- deg[dst] += ew ; count in-edges per node ----
__global__ void k_deg2(const int* __restrict__ dst, const float* __restrict__ ew,
                       float* __restrict__ deg, int* __restrict__ cntN, int E){
  int e = blockIdx.x*256 + threadIdx.x;
  if (e >= E) return;
  int d = dst[e];
  atomicAdd(&deg[d], ew[e]);
  atomicAdd(&cntN[d], 1);
}

// ---- dis = rsqrt(deg) in place (deg >= 1 due to self-loops) ----
__global__ void k_dis(float* __restrict__ deg, int N){
  int i = blockIdx.x*256 + threadIdx.x;
  if (i < N) deg[i] = rsqrtf(deg[i]);
}

// ==== CSR build: 3-kernel exclusive scan over cntN, then fill ====
__global__ __launch_bounds__(256) void k_scan_partial(const int* __restrict__ cnt,
        int* __restrict__ bsum, int N){
  __shared__ int red[256];
  int t = threadIdx.x, i = blockIdx.x*256 + t;
  red[t] = (i < N) ? cnt[i] : 0;
  __syncthreads();
  for (int s = 128; s > 0; s >>= 1){ if (t < s) red[t] += red[t+s]; __syncthreads(); }
  if (t == 0) bsum[blockIdx.x] = red[0];
}

__global__ __launch_bounds__(256) void k_scan_bsum(int* __restrict__ bsum, int nb,
        int* __restrict__ row_start, int N, int E){
  __shared__ int sc[256];
  int t = threadIdx.x;
  int orig = (t < nb) ? bsum[t] : 0;
  sc[t] = orig;
  __syncthreads();
  for (int off = 1; off < 256; off <<= 1){
    int v = (t >= off) ? sc[t-off] : 0;
    __syncthreads();
    sc[t] += v;
    __syncthreads();
  }
  if (t < nb) bsum[t] = sc[t] - orig;   // exclusive
  if (t == 0) row_start[N] = E;
}

__global__ __launch_bounds__(256) void k_scan_final(const int* __restrict__ cnt,
        const int* __restrict__ bsum, int* __restrict__ row_start,
        int* __restrict__ cursor, int N){
  __shared__ int sc[256];
  int t = threadIdx.x, i = blockIdx.x*256 + t;
  int orig = (i < N) ? cnt[i] : 0;
  sc[t] = orig;
  __syncthreads();
  for (int off = 1; off < 256; off <<= 1){
    int v = (t >= off) ? sc[t-off] : 0;
    __syncthreads();
    sc[t] += v;
    __syncthreads();
  }
  if (i < N){
    int ex = bsum[blockIdx.x] + sc[t] - orig;
    row_start[i] = ex;
    cursor[i]    = ex;
  }
}

// ---- fill CSR: es[pos]=src, wn[pos]=dis[src]*ew*dis[dst] ----
__global__ void k_fill(const int* __restrict__ src, const int* __restrict__ dst,
        const float* __restrict__ ew, const float* __restrict__ dis,
        int* __restrict__ cursor, int* __restrict__ es, float* __restrict__ wn, int E){
  int e = blockIdx.x*256 + threadIdx.x;
  if (e >= E) return;
  int s = src[e], d = dst[e];
  int pos = atomicAdd(&cursor[d], 1);
  es[pos] = s;
  wn[pos] = dis[s] * ew[e] * dis[d];
}

// ---- pull aggregation: xo[n] = bias + dis[n]^2*xw[n] + sum_j wn[j]*xw[es[j]] ----
__global__ __launch_bounds__(128) void k_agg(const float* __restrict__ xw,
        const int* __restrict__ row_start, const int* __restrict__ es,
        const float* __restrict__ wn, const float* __restrict__ dis,
        const float* __restrict__ bias, float* __restrict__ xo, int N){
  int n = blockIdx.x, d = threadIdx.x;
  float dv = dis[n];
  float acc = bias[d] + xw[(size_t)n*Dc + d]*dv*dv;
  int j = row_start[n], j1 = row_start[n+1];
  for (; j + 1 < j1; j += 2){
    int   s0 = es[j],  s1 = es[j+1];
    float w0 = wn[j],  w1 = wn[j+1];
    acc += xw[(size_t)s0*Dc + d]*w0 + xw[(size_t)s1*Dc + d]*w1;
  }
  if (j < j1) acc += xw[(size_t)es[j]*Dc + d]*wn[j];
  xo[(size_t)n*Dc + d] = acc;
}

// ==== image GEMM v3: LDS-staged images, no atomics, partials ====
// block: 256 threads x 2 cols = 512 cols; one K-segment of KS3 per block.
// P[segy*BI + b*IMG + col] = sum_{k in seg} images[b,k] * W[k,col]
constexpr int KS3 = 64;
__global__ __launch_bounds__(256) void k_img_mm3(const float* __restrict__ images,
        const float* __restrict__ Wimg, float* __restrict__ P, int IMG){
  __shared__ float Ls[NG][KS3];
  int t = threadIdx.x;
  int col = blockIdx.x*512 + (t << 1);
  int k0  = blockIdx.y * KS3;
  for (int i = t; i < NG*KS3; i += 256){
    int b = i >> 6, k = i & (KS3-1);
    Ls[b][k] = images[(size_t)b*IMG + k0 + k];
  }
  __syncthreads();
  float2 acc[NG];
  #pragma unroll
  for (int b = 0; b < NG; b++){ acc[b].x = 0.f; acc[b].y = 0.f; }
  const float* wp = Wimg + (size_t)k0*IMG + col;
  for (int k = 0; k < KS3; k += 2){
    float2 w0 = *(const float2*)wp;
    float2 w1 = *(const float2*)(wp + IMG);
    wp += 2*(size_t)IMG;
    #pragma unroll
    for (int b = 0; b < NG; b++){
      float2 iv = *(const float2*)&Ls[b][k];   // broadcast ds_read_b64
      acc[b].x += iv.x*w0.x + iv.y*w1.x;
      acc[b].y += iv.x*w0.y + iv.y*w1.y;
    }
  }
  size_t base = (size_t)blockIdx.y*NG*IMG + col;
  #pragma unroll
  for (int b = 0; b < NG; b++)
    *(float2*)&P[base + (size_t)b*IMG] = acc[b];
}

// ---- q[i] += sum_seg P[seg*BI + i]  (q pre-initialized to bias) ----
__global__ __launch_bounds__(256) void k_img_reduce(const float* __restrict__ P,
        float* __restrict__ q, int BI, int nseg){
  int i = blockIdx.x*256 + threadIdx.x;
  if (i >= BI) return;
  float s = q[i];
  for (int g = 0; g < nseg; g++) s += P[(size_t)g*BI + i];
  q[i] = s;
}

// ---- legacy image GEMM (fallback): split-K + LDS staging + atomics ----
constexpr int KCH = 32;
__global__ __launch_bounds__(256) void k_img_mm_legacy(const float* __restrict__ images,
        const float* __restrict__ Wimg, float* __restrict__ q, int IMG, int KSEG){
  __shared__ float Ls[KCH][NG];
  int col = blockIdx.x*256 + threadIdx.x;
  int k0  = blockIdx.y * KSEG;
  float acc[NG];
  #pragma unroll
  for (int b = 0; b < NG; b++) acc[b] = 0.f;
  for (int kk = k0; kk < k0 + KSEG; kk += KCH){
    int t = threadIdx.x;
    for (int i = t; i < KCH*NG; i += 256){
      int b = i & (NG-1), k = i >> 5;
      Ls[k][b] = images[(size_t)b*IMG + kk + k];
    }
    __syncthreads();
    for (int k = 0; k < KCH; k++){
      float w = Wimg[(size_t)(kk+k)*IMG + col];
      #pragma unroll
      for (int b = 0; b < NG; b++) acc[b] += Ls[k][b] * w;
    }
    __syncthreads();
  }
  for (int b = 0; b < NG; b++) atomicAdd(&q[(size_t)b*IMG + col], acc[b]);
}

// ---- image head, split-K: qi[b,d] += sum_{k in seg} q[b,k] * Wi[k,d] ----
constexpr int IKS = 16;   // K segments
__global__ __launch_bounds__(128) void k_ihead_mm(const float* __restrict__ q,
        const float* __restrict__ Wi, float* __restrict__ qi, int IMG){
  int b = blockIdx.x, seg = blockIdx.y, d = threadIdx.x;
  int kseg = IMG / IKS;
  const float* qr = q  + (size_t)b*IMG + (size_t)seg*kseg;
  const float* wr = Wi + (size_t)seg*kseg*Dc + d;
  float acc = 0.f;
  for (int k = 0; k < kseg; k++) acc += qr[k] * wr[(size_t)k*Dc];  // qr uniform, wr coalesced
  atomicAdd(&qi[b*Dc + d], acc);
}

// ---- out_images = l2norm(qi) ----
__global__ __launch_bounds__(128) void k_ihead_norm(const float* __restrict__ qi,
        float* __restrict__ out){
  int b = blockIdx.x, d = threadIdx.x;
  float v = qi[b*Dc + d];
  __shared__ float red[Dc];
  red[d] = v*v; __syncthreads();
  for (int s = Dc/2; s > 0; s >>= 1){ if (d < s) red[d] += red[d+s]; __syncthreads(); }
  out[b*Dc + d] = v * rsqrtf(red[0]);
}

// ---- xw = (relu?)x @ W  -- 4 rows/thread share one ds_read_b128 per k.
// NOTE: R9's float4-x + manual 4x unroll spilled (VGPR 256, 620 MB scratch).
// This keeps scalar x loads (proven) and only widens row reuse: ~40 VGPR.
__global__ __launch_bounds__(256) void k_mm(const float* __restrict__ x,
        const float* __restrict__ W, float* __restrict__ xw, int N, int relu){
  __shared__ float Ws[Dc*Dc];
  int t = threadIdx.x;
  for (int i = t; i < Dc*Dc; i += 256) Ws[i] = W[i];
  __syncthreads();
  int rg = t >> 5, c4 = (t & 31) << 2;
  int n0 = blockIdx.x*32 + rg;              // rows n0, n0+8, n0+16, n0+24
  int n1 = n0 + 8, n2 = n0 + 16, n3 = n0 + 24;
  bool v0 = n0 < N, v1 = n1 < N, v2 = n2 < N, v3 = n3 < N;
  const float* x0 = x + (size_t)(v0 ? n0 : 0)*Dc;
  const float* x1 = x + (size_t)(v1 ? n1 : 0)*Dc;
  const float* x2 = x + (size_t)(v2 ? n2 : 0)*Dc;
  const float* x3 = x + (size_t)(v3 ? n3 : 0)*Dc;
  float4 a0 = {0,0,0,0}, a1 = a0, a2 = a0, a3 = a0;
  for (int k = 0; k < Dc; k++){
    const float4 w = *(const float4*)&Ws[k*Dc + c4];
    float xv0 = x0[k], xv1 = x1[k], xv2 = x2[k], xv3 = x3[k];
    if (relu){
      xv0 = fmaxf(xv0, 0.f); xv1 = fmaxf(xv1, 0.f);
      xv2 = fmaxf(xv2, 0.f); xv3 = fmaxf(xv3, 0.f);
    }
    a0.x += xv0*w.x; a0.y += xv0*w.y; a0.z += xv0*w.z; a0.w += xv0*w.w;
    a1.x += xv1*w.x; a1.y += xv1*w.y; a1.z += xv1*w.z; a1.w += xv1*w.w;
    a2.x += xv2*w.x; a2.y += xv2*w.y; a2.z += xv2*w.z; a2.w += xv2*w.w;
    a3.x += xv3*w.x; a3.y += xv3*w.y; a3.z += xv3*w.z; a3.w += xv3*w.w;
  }
  if (v0) *(float4*)&xw[(size_t)n0*Dc + c4] = a0;
  if (v1) *(float4*)&xw[(size_t)n1*Dc + c4] = a1;
  if (v2) *(float4*)&xw[(size_t)n2*Dc + c4] = a2;
  if (v3) *(float4*)&xw[(size_t)n3*Dc + c4] = a3;
}

// ---- mean pool by graph (batch sorted); flush only block's graph range ----
__global__ __launch_bounds__(128) void k_pool(const float* __restrict__ x,
        const int* __restrict__ batch, float* __restrict__ pooled,
        float* __restrict__ cnt, int N){
  __shared__ float acc[NG*Dc];
  __shared__ float cl[NG];
  int t = threadIdx.x;
  int chunk = (N + gridDim.x - 1) / gridDim.x;
  int s = blockIdx.x*chunk;
  int e = min(N, s + chunk);
  if (s >= e) return;                 // whole block exits together
  for (int i = t; i < NG*Dc; i += 128) acc[i] = 0.f;
  if (t < NG) cl[t] = 0.f;
  __syncthreads();
  for (int n = s; n < e; n++){
    int g = batch[n];
    acc[g*Dc + t] += x[(size_t)n*Dc + t];
    if (t == 0) cl[g] += 1.f;
  }
  __syncthreads();
  int gmin = batch[s], gmax = batch[e-1];
  for (int g = gmin; g <= gmax; g++) atomicAdd(&pooled[g*Dc + t], acc[g*Dc + t]);
  if (t >= gmin && t <= gmax) atomicAdd(&cnt[t], cl[t]);
}

// ---- out_graphs = l2norm((pooled/cnt) @ W_g + b_g) ----
__global__ __launch_bounds__(128) void k_head(const float* __restrict__ pooled,
        const float* __restrict__ cnt, const float* __restrict__ Wg,
        const float* __restrict__ bg, float* __restrict__ outg){
  int g = blockIdx.x, t = threadIdx.x;
  __shared__ float m[Dc];
  __shared__ float red[Dc];
  float c = fmaxf(cnt[g], 1.f);
  m[t] = pooled[g*Dc + t] / c;
  __syncthreads();
  float acc = bg[t];
  for (int k = 0; k < Dc; k++) acc += m[k] * Wg[k*Dc + t];
  red[t] = acc*acc; __syncthreads();
  for (int s = Dc/2; s > 0; s >>= 1){ if (t < s) red[t] += red[t+s]; __syncthreads(); }
  outg[g*Dc + t] = acc * rsqrtf(red[0]);
}

extern "C" void kernel_launch(void* const* d_in, const int* in_sizes, int n_in,
                              void* d_out, int out_size, void* d_ws, size_t ws_size,
                              hipStream_t stream){
  float* out = (float*)d_out;   // reference outputs are float32

  // ---- dict-order signature verification; absmax ~= 700+code names first bad slot ----
  int fail = 0;
  auto chk = [&](bool ok, int code){ if (!fail && !ok) fail = code; };
  chk(n_in == 19, 1);
  int IMG = 0, N = 0, E = 0;
  if (!fail){
    IMG = in_sizes[0] / NG;                     // images = [NG, IMG]
    N   = in_sizes[1];                          // node_ids
    E   = in_sizes[2];                          // src
    chk(IMG >= 256 && (IMG % 256) == 0 && in_sizes[0] == NG*IMG, 2);
    chk(in_sizes[3] == E && in_sizes[4] == E, 3);        // dst, edge_attr
    chk(in_sizes[5] == N, 4);                            // batch
    chk(in_sizes[6] > 0 && (in_sizes[6] % Dc) == 0, 5);  // node_emb [VOCAB, 128]
    chk((long long)in_sizes[7] == (long long)IMG*IMG, 6);// W_img
    chk(in_sizes[8] == IMG, 7);                          // b_img
    chk((long long)in_sizes[9] == (long long)IMG*Dc, 8); // W_i
    chk(in_sizes[10] == Dc, 9);                          // b_i
    chk(in_sizes[11] == Dc*Dc && in_sizes[13] == Dc*Dc &&
        in_sizes[15] == Dc*Dc && in_sizes[17] == Dc*Dc, 10); // W1..W3, W_g
    chk(in_sizes[12] == Dc && in_sizes[14] == Dc &&
        in_sizes[16] == Dc && in_sizes[18] == Dc, 11);       // b1..b3, b_g
    chk(out_size == 2*NG*Dc, 12);
  }
  if (fail){
    k_sentinel<<<(out_size+255)/256, 256, 0, stream>>>(out, 700.f + (float)fail, out_size);
    return;
  }

  const float* images   = (const float*)d_in[0];
  const int*   node_ids = (const int*)  d_in[1];
  const int*   src      = (const int*)  d_in[2];
  const int*   dst      = (const int*)  d_in[3];
  const float* eattr    = (const float*)d_in[4];
  const int*   batch    = (const int*)  d_in[5];
  const float* emb      = (const float*)d_in[6];
  const float* W_img    = (const float*)d_in[7];
  const float* b_img    = (const float*)d_in[8];
  const float* W_i      = (const float*)d_in[9];
  const float* b_i      = (const float*)d_in[10];
  const float* W1       = (const float*)d_in[11];
  const float* b1       = (const float*)d_in[12];
  const float* W2       = (const float*)d_in[13];
  const float* b2       = (const float*)d_in[14];
  const float* W3       = (const float*)d_in[15];
  const float* b3       = (const float*)d_in[16];
  const float* W_g      = (const float*)d_in[17];
  const float* b_g      = (const float*)d_in[18];

  const int BI = NG * IMG;
  const int ND = N * Dc;
  const int nb = (N + 255) / 256;     // scan blocks

  // ---- workspace layout: common fp32 region, then CSR int region ----
  size_t common = 2*(size_t)ND + E + N + BI + NG*Dc + NG + NG*Dc;   // floats
  size_t csr_i  = (size_t)E + (N+1) + N + N + 256;                   // ints
  size_t need   = common*sizeof(float) + csr_i*sizeof(int);
  if (ws_size < need || nb > 256){
    k_sentinel<<<(out_size+255)/256, 256, 0, stream>>>(out, 690.f, out_size);
    return;
  }

  float* ws    = (float*)d_ws;
  float* xA    = ws;  ws += (size_t)ND;
  float* xw    = ws;  ws += (size_t)ND;
  float* wn    = ws;  ws += E;          // CSR weights
  float* dis   = ws;  ws += N;          // holds deg first, then rsqrt in place
  float* q     = ws;  ws += BI;
  float* pooled= ws;  ws += NG*Dc;
  float* cnt   = ws;  ws += NG;
  float* qi    = ws;  ws += NG*Dc;
  int* iw        = (int*)ws;
  int* es        = iw;  iw += E;        // CSR src indices
  int* row_start = iw;  iw += N+1;
  int* cursor    = iw;  iw += N;
  int* cntN      = iw;  iw += N;
  int* bsum      = iw;  iw += 256;

  float* P = xA;   // image-GEMM partials live in [xA, xA+2*ND+E) BEFORE graph path

  k_init<<<(BI+255)/256, 256, 0, stream>>>(b_img, q, dis, pooled, b_i, qi, cntN, BI, IMG, N);

  // ---- image path first (partials reuse the xA/xw/wn region) ----
  int nseg = IMG / KS3;
  bool v3ok = ((IMG % 512) == 0) && ((size_t)nseg*BI <= 2*(size_t)ND + E);
  if (v3ok){
    k_img_mm3   <<<dim3(IMG/512, nseg), 256, 0, stream>>>(images, W_img, P, IMG);
    k_img_reduce<<<(BI+255)/256, 256, 0, stream>>>(P, q, BI, nseg);
  } else {
    const int KSPLIT = ((IMG % (16*KCH)) == 0) ? 16 : 8;
    k_img_mm_legacy<<<dim3(IMG/256, KSPLIT), 256, 0, stream>>>(images, W_img, q, IMG, IMG/KSPLIT);
  }
  k_ihead_mm  <<<dim3(NG, IKS), Dc, 0, stream>>>(q, W_i, qi, IMG);
  k_ihead_norm<<<NG, Dc, 0, stream>>>(qi, out);

  // ---- graph path ----
  k_gather<<<(ND+255)/256, 256, 0, stream>>>(emb, node_ids, xA, ND);
  k_deg2  <<<(E+255)/256, 256, 0, stream>>>(dst, eattr, dis, cntN, E);
  k_dis   <<<(N+255)/256, 256, 0, stream>>>(dis, N);
  k_scan_partial<<<nb, 256, 0, stream>>>(cntN, bsum, N);
  k_scan_bsum   <<<1,  256, 0, stream>>>(bsum, nb, row_start, N, E);
  k_scan_final  <<<nb, 256, 0, stream>>>(cntN, bsum, row_start, cursor, N);
  k_fill        <<<(E+255)/256, 256, 0, stream>>>(src, dst, eattr, dis, cursor, es, wn, E);

  const float* Wl[3] = {W1, W2, W3};
  const float* bl[3] = {b1, b2, b3};
  for (int l = 0; l < 3; l++){
    k_mm <<<(N+31)/32, 256, 0, stream>>>(xA, Wl[l], xw, N, l > 0);
    k_agg<<<N, Dc, 0, stream>>>(xw, row_start, es, wn, dis, bl[l], xA, N);
  }

  k_pool<<<256, Dc, 0, stream>>>(xA, batch, pooled, cnt, N);
  k_head<<<NG, Dc, 0, stream>>>(pooled, cnt, W_g, b_g, out + NG*Dc);
}

// Round 12
// 662.744 us; speedup vs baseline: 2.5905x; 1.1471x over previous
//
#include <hip/hip_runtime.h>
#include <hip/hip_bf16.h>

constexpr int Dc = 128;   // feature dim
constexpr int NG = 32;    // num graphs / batch size

// ---- sentinel: encode a diagnostic code in the output magnitude ----
__global__ void k_sentinel(float* __restrict__ out, float val, int n){
  int i = blockIdx.x*256 + threadIdx.x;
  if (i < n) out[i] = val;
}

// ---- init: q = b_img, deg = 1.0 (self-loop weight), pooled/cnt = 0, qi = b_i, cntN = 0 ----
__global__ void k_init(const float* __restrict__ b_img, float* __restrict__ q,
                       float* __restrict__ deg, float* __restrict__ pooled,
                       const float* __restrict__ b_i, float* __restrict__ qi,
                       int* __restrict__ cntN, int BI, int IMG, int N){
  int i = blockIdx.x*256 + threadIdx.x;
  if (i < BI) q[i] = b_img[i % IMG];
  if (i < N){ deg[i] = 1.0f; cntN[i] = 0; }
  if (i < NG*Dc + NG) pooled[i] = 0.f;   // pooled followed by cnt
  if (i < NG*Dc) qi[i] = b_i[i & (Dc-1)];
}

// ---- x0 = node_emb[node_ids] ----
__global__ void k_gather(const float* __restrict__ emb, const int* __restrict__ ids,
                         float* __restrict__ x, int ND){
  int i = blockIdx.x*256 + threadIdx.x;
  if (i >= ND) return;
  int n = i >> 7, d = i & (Dc-1);
  x[i] = emb[(size_t)ids[n]*Dc + d];
}

// ---- deg[dst] += ew ; count in-edges per node ----
__global__ void k_deg2(const int* __restrict__ dst, const float* __restrict__ ew,
                       float* __restrict__ deg, int* __restrict__ cntN, int E){
  int e = blockIdx.x*256 + threadIdx.x;
  if (e >= E) return;
  int d = dst[e];
  atomicAdd(&deg[d], ew[e]);
  atomicAdd(&cntN[d], 1);
}

// ---- dis = rsqrt(deg) in place (deg >= 1 due to self-loops) ----
__global__ void k_dis(float* __restrict__ deg, int N){
  int i = blockIdx.x*256 + threadIdx.x;
  if (i < N) deg[i] = rsqrtf(deg[i]);
}

// ==== CSR build: 3-kernel exclusive scan over cntN, then fill ====
__global__ __launch_bounds__(256) void k_scan_partial(const int* __restrict__ cnt,
        int* __restrict__ bsum, int N){
  __shared__ int red[256];
  int t = threadIdx.x, i = blockIdx.x*256 + t;
  red[t] = (i < N) ? cnt[i] : 0;
  __syncthreads();
  for (int s = 128; s > 0; s >>= 1){ if (t < s) red[t] += red[t+s]; __syncthreads(); }
  if (t == 0) bsum[blockIdx.x] = red[0];
}

__global__ __launch_bounds__(256) void k_scan_bsum(int* __restrict__ bsum, int nb,
        int* __restrict__ row_start, int N, int E){
  __shared__ int sc[256];
  int t = threadIdx.x;
  int orig = (t < nb) ? bsum[t] : 0;
  sc[t] = orig;
  __syncthreads();
  for (int off = 1; off < 256; off <<= 1){
    int v = (t >= off) ? sc[t-off] : 0;
    __syncthreads();
    sc[t] += v;
    __syncthreads();
  }
  if (t < nb) bsum[t] = sc[t] - orig;   // exclusive
  if (t == 0) row_start[N] = E;
}

__global__ __launch_bounds__(256) void k_scan_final(const int* __restrict__ cnt,
        const int* __restrict__ bsum, int* __restrict__ row_start,
        int* __restrict__ cursor, int N){
  __shared__ int sc[256];
  int t = threadIdx.x, i = blockIdx.x*256 + t;
  int orig = (i < N) ? cnt[i] : 0;
  sc[t] = orig;
  __syncthreads();
  for (int off = 1; off < 256; off <<= 1){
    int v = (t >= off) ? sc[t-off] : 0;
    __syncthreads();
    sc[t] += v;
    __syncthreads();
  }
  if (i < N){
    int ex = bsum[blockIdx.x] + sc[t] - orig;
    row_start[i] = ex;
    cursor[i]    = ex;
  }
}

// ---- fill CSR: es[pos]=src, wn[pos]=dis[src]*ew*dis[dst] ----
__global__ void k_fill(const int* __restrict__ src, const int* __restrict__ dst,
        const float* __restrict__ ew, const float* __restrict__ dis,
        int* __restrict__ cursor, int* __restrict__ es, float* __restrict__ wn, int E){
  int e = blockIdx.x*256 + threadIdx.x;
  if (e >= E) return;
  int s = src[e], d = dst[e];
  int pos = atomicAdd(&cursor[d], 1);
  es[pos] = s;
  wn[pos] = dis[s] * ew[e] * dis[d];
}

// ---- pull aggregation (unroll 4: four independent gather chains in flight) ----
__global__ __launch_bounds__(128) void k_agg(const float* __restrict__ xw,
        const int* __restrict__ row_start, const int* __restrict__ es,
        const float* __restrict__ wn, const float* __restrict__ dis,
        const float* __restrict__ bias, float* __restrict__ xo, int N){
  int n = blockIdx.x, d = threadIdx.x;
  float dv = dis[n];
  float acc = bias[d] + xw[(size_t)n*Dc + d]*dv*dv;
  int j = row_start[n], j1 = row_start[n+1];
  for (; j + 3 < j1; j += 4){
    int   s0 = es[j],   s1 = es[j+1], s2 = es[j+2], s3 = es[j+3];
    float w0 = wn[j],   w1 = wn[j+1], w2 = wn[j+2], w3 = wn[j+3];
    acc += xw[(size_t)s0*Dc + d]*w0 + xw[(size_t)s1*Dc + d]*w1
         + xw[(size_t)s2*Dc + d]*w2 + xw[(size_t)s3*Dc + d]*w3;
  }
  for (; j < j1; j++) acc += xw[(size_t)es[j]*Dc + d]*wn[j];
  xo[(size_t)n*Dc + d] = acc;
}

// ==== image GEMM v3: LDS-staged images, no atomics, partials ====
constexpr int KS3 = 64;
__global__ __launch_bounds__(256) void k_img_mm3(const float* __restrict__ images,
        const float* __restrict__ Wimg, float* __restrict__ P, int IMG){
  __shared__ float Ls[NG][KS3];
  int t = threadIdx.x;
  int col = blockIdx.x*512 + (t << 1);
  int k0  = blockIdx.y * KS3;
  for (int i = t; i < NG*KS3; i += 256){
    int b = i >> 6, k = i & (KS3-1);
    Ls[b][k] = images[(size_t)b*IMG + k0 + k];
  }
  __syncthreads();
  float2 acc[NG];
  #pragma unroll
  for (int b = 0; b < NG; b++){ acc[b].x = 0.f; acc[b].y = 0.f; }
  const float* wp = Wimg + (size_t)k0*IMG + col;
  for (int k = 0; k < KS3; k += 2){
    float2 w0 = *(const float2*)wp;
    float2 w1 = *(const float2*)(wp + IMG);
    wp += 2*(size_t)IMG;
    #pragma unroll
    for (int b = 0; b < NG; b++){
      float2 iv = *(const float2*)&Ls[b][k];   // broadcast ds_read_b64
      acc[b].x += iv.x*w0.x + iv.y*w1.x;
      acc[b].y += iv.x*w0.y + iv.y*w1.y;
    }
  }
  size_t base = (size_t)blockIdx.y*NG*IMG + col;
  #pragma unroll
  for (int b = 0; b < NG; b++)
    *(float2*)&P[base + (size_t)b*IMG] = acc[b];
}

// ---- q[i] += sum_seg P[seg*BI + i]  (q pre-initialized to bias) ----
__global__ __launch_bounds__(256) void k_img_reduce(const float* __restrict__ P,
        float* __restrict__ q, int BI, int nseg){
  int i = blockIdx.x*256 + threadIdx.x;
  if (i >= BI) return;
  float s = q[i];
  for (int g = 0; g < nseg; g++) s += P[(size_t)g*BI + i];
  q[i] = s;
}

// ---- legacy image GEMM (fallback): split-K + LDS staging + atomics ----
constexpr int KCH = 32;
__global__ __launch_bounds__(256) void k_img_mm_legacy(const float* __restrict__ images,
        const float* __restrict__ Wimg, float* __restrict__ q, int IMG, int KSEG){
  __shared__ float Ls[KCH][NG];
  int col = blockIdx.x*256 + threadIdx.x;
  int k0  = blockIdx.y * KSEG;
  float acc[NG];
  #pragma unroll
  for (int b = 0; b < NG; b++) acc[b] = 0.f;
  for (int kk = k0; kk < k0 + KSEG; kk += KCH){
    int t = threadIdx.x;
    for (int i = t; i < KCH*NG; i += 256){
      int b = i & (NG-1), k = i >> 5;
      Ls[k][b] = images[(size_t)b*IMG + kk + k];
    }
    __syncthreads();
    for (int k = 0; k < KCH; k++){
      float w = Wimg[(size_t)(kk+k)*IMG + col];
      #pragma unroll
      for (int b = 0; b < NG; b++) acc[b] += Ls[k][b] * w;
    }
    __syncthreads();
  }
  for (int b = 0; b < NG; b++) atomicAdd(&q[(size_t)b*IMG + col], acc[b]);
}

// ---- image head v2: 64-way split-K, q segment staged in LDS ----
constexpr int IKS2 = 64;
__global__ __launch_bounds__(128) void k_ihead_mm2(const float* __restrict__ q,
        const float* __restrict__ Wi, float* __restrict__ qi, int IMG){
  int b = blockIdx.x, seg = blockIdx.y, d = threadIdx.x;
  int kseg = IMG / IKS2;
  __shared__ float Lq[256];
  for (int i = d; i < kseg; i += 128) Lq[i] = q[(size_t)b*IMG + (size_t)seg*kseg + i];
  __syncthreads();
  const float* wr = Wi + (size_t)seg*kseg*Dc + d;
  float acc = 0.f;
  for (int k = 0; k < kseg; k++) acc += Lq[k] * wr[(size_t)k*Dc];  // LDS broadcast + coalesced
  atomicAdd(&qi[b*Dc + d], acc);
}

// ---- legacy image head (fallback): 16-way split-K, uniform q loads ----
constexpr int IKS = 16;
__global__ __launch_bounds__(128) void k_ihead_mm(const float* __restrict__ q,
        const float* __restrict__ Wi, float* __restrict__ qi, int IMG){
  int b = blockIdx.x, seg = blockIdx.y, d = threadIdx.x;
  int kseg = IMG / IKS;
  const float* qr = q  + (size_t)b*IMG + (size_t)seg*kseg;
  const float* wr = Wi + (size_t)seg*kseg*Dc + d;
  float acc = 0.f;
  for (int k = 0; k < kseg; k++) acc += qr[k] * wr[(size_t)k*Dc];
  atomicAdd(&qi[b*Dc + d], acc);
}

// ---- out_images = l2norm(qi) ----
__global__ __launch_bounds__(128) void k_ihead_norm(const float* __restrict__ qi,
        float* __restrict__ out){
  int b = blockIdx.x, d = threadIdx.x;
  float v = qi[b*Dc + d];
  __shared__ float red[Dc];
  red[d] = v*v; __syncthreads();
  for (int s = Dc/2; s > 0; s >>= 1){ if (d < s) red[d] += red[d+s]; __syncthreads(); }
  out[b*Dc + d] = v * rsqrtf(red[0]);
}

// ---- xw = (relu?)x @ W  -- 4 rows/thread share one ds_read_b128 per k ----
__global__ __launch_bounds__(256) void k_mm(const float* __restrict__ x,
        const float* __restrict__ W, float* __restrict__ xw, int N, int relu){
  __shared__ float Ws[Dc*Dc];
  int t = threadIdx.x;
  for (int i = t; i < Dc*Dc; i += 256) Ws[i] = W[i];
  __syncthreads();
  int rg = t >> 5, c4 = (t & 31) << 2;
  int n0 = blockIdx.x*32 + rg;              // rows n0, n0+8, n0+16, n0+24
  int n1 = n0 + 8, n2 = n0 + 16, n3 = n0 + 24;
  bool v0 = n0 < N, v1 = n1 < N, v2 = n2 < N, v3 = n3 < N;
  const float* x0 = x + (size_t)(v0 ? n0 : 0)*Dc;
  const float* x1 = x + (size_t)(v1 ? n1 : 0)*Dc;
  const float* x2 = x + (size_t)(v2 ? n2 : 0)*Dc;
  const float* x3 = x + (size_t)(v3 ? n3 : 0)*Dc;
  float4 a0 = {0,0,0,0}, a1 = a0, a2 = a0, a3 = a0;
  for (int k = 0; k < Dc; k++){
    const float4 w = *(const float4*)&Ws[k*Dc + c4];
    float xv0 = x0[k], xv1 = x1[k], xv2 = x2[k], xv3 = x3[k];
    if (relu){
      xv0 = fmaxf(xv0, 0.f); xv1 = fmaxf(xv1, 0.f);
      xv2 = fmaxf(xv2, 0.f); xv3 = fmaxf(xv3, 0.f);
    }
    a0.x += xv0*w.x; a0.y += xv0*w.y; a0.z += xv0*w.z; a0.w += xv0*w.w;
    a1.x += xv1*w.x; a1.y += xv1*w.y; a1.z += xv1*w.z; a1.w += xv1*w.w;
    a2.x += xv2*w.x; a2.y += xv2*w.y; a2.z += xv2*w.z; a2.w += xv2*w.w;
    a3.x += xv3*w.x; a3.y += xv3*w.y; a3.z += xv3*w.z; a3.w += xv3*w.w;
  }
  if (v0) *(float4*)&xw[(size_t)n0*Dc + c4] = a0;
  if (v1) *(float4*)&xw[(size_t)n1*Dc + c4] = a1;
  if (v2) *(float4*)&xw[(size_t)n2*Dc + c4] = a2;
  if (v3) *(float4*)&xw[(size_t)n3*Dc + c4] = a3;
}

// ---- mean pool by graph (batch sorted); flush only block's graph range ----
__global__ __launch_bounds__(128) void k_pool(const float* __restrict__ x,
        const int* __restrict__ batch, float* __restrict__ pooled,
        float* __restrict__ cnt, int N){
  __shared__ float acc[NG*Dc];
  __shared__ float cl[NG];
  int t = threadIdx.x;
  int chunk = (N + gridDim.x - 1) / gridDim.x;
  int s = blockIdx.x*chunk;
  int e = min(N, s + chunk);
  if (s >= e) return;                 // whole block exits together
  for (int i = t; i < NG*Dc; i += 128) acc[i] = 0.f;
  if (t < NG) cl[t] = 0.f;
  __syncthreads();
  for (int n = s; n < e; n++){
    int g = batch[n];
    acc[g*Dc + t] += x[(size_t)n*Dc + t];
    if (t == 0) cl[g] += 1.f;
  }
  __syncthreads();
  int gmin = batch[s], gmax = batch[e-1];
  for (int g = gmin; g <= gmax; g++) atomicAdd(&pooled[g*Dc + t], acc[g*Dc + t]);
  if (t >= gmin && t <= gmax) atomicAdd(&cnt[t], cl[t]);
}

// ---- out_graphs = l2norm((pooled/cnt) @ W_g + b_g) ----
__global__ __launch_bounds__(128) void k_head(const float* __restrict__ pooled,
        const float* __restrict__ cnt, const float* __restrict__ Wg,
        const float* __restrict__ bg, float* __restrict__ outg){
  int g = blockIdx.x, t = threadIdx.x;
  __shared__ float m[Dc];
  __shared__ float red[Dc];
  float c = fmaxf(cnt[g], 1.f);
  m[t] = pooled[g*Dc + t] / c;
  __syncthreads();
  float acc = bg[t];
  for (int k = 0; k < Dc; k++) acc += m[k] * Wg[k*Dc + t];
  red[t] = acc*acc; __syncthreads();
  for (int s = Dc/2; s > 0; s >>= 1){ if (t < s) red[t] += red[t+s]; __syncthreads(); }
  outg[g*Dc + t] = acc * rsqrtf(red[0]);
}

extern "C" void kernel_launch(void* const* d_in, const int* in_sizes, int n_in,
                              void* d_out, int out_size, void* d_ws, size_t ws_size,
                              hipStream_t stream){
  float* out = (float*)d_out;   // reference outputs are float32

  // ---- dict-order signature verification; absmax ~= 700+code names first bad slot ----
  int fail = 0;
  auto chk = [&](bool ok, int code){ if (!fail && !ok) fail = code; };
  chk(n_in == 19, 1);
  int IMG = 0, N = 0, E = 0;
  if (!fail){
    IMG = in_sizes[0] / NG;                     // images = [NG, IMG]
    N   = in_sizes[1];                          // node_ids
    E   = in_sizes[2];                          // src
    chk(IMG >= 256 && (IMG % 256) == 0 && in_sizes[0] == NG*IMG, 2);
    chk(in_sizes[3] == E && in_sizes[4] == E, 3);        // dst, edge_attr
    chk(in_sizes[5] == N, 4);                            // batch
    chk(in_sizes[6] > 0 && (in_sizes[6] % Dc) == 0, 5);  // node_emb [VOCAB, 128]
    chk((long long)in_sizes[7] == (long long)IMG*IMG, 6);// W_img
    chk(in_sizes[8] == IMG, 7);                          // b_img
    chk((long long)in_sizes[9] == (long long)IMG*Dc, 8); // W_i
    chk(in_sizes[10] == Dc, 9);                          // b_i
    chk(in_sizes[11] == Dc*Dc && in_sizes[13] == Dc*Dc &&
        in_sizes[15] == Dc*Dc && in_sizes[17] == Dc*Dc, 10); // W1..W3, W_g
    chk(in_sizes[12] == Dc && in_sizes[14] == Dc &&
        in_sizes[16] == Dc && in_sizes[18] == Dc, 11);       // b1..b3, b_g
    chk(out_size == 2*NG*Dc, 12);
  }
  if (fail){
    k_sentinel<<<(out_size+255)/256, 256, 0, stream>>>(out, 700.f + (float)fail, out_size);
    return;
  }

  const float* images   = (const float*)d_in[0];
  const int*   node_ids = (const int*)  d_in[1];
  const int*   src      = (const int*)  d_in[2];
  const int*   dst      = (const int*)  d_in[3];
  const float* eattr    = (const float*)d_in[4];
  const int*   batch    = (const int*)  d_in[5];
  const float* emb      = (const float*)d_in[6];
  const float* W_img    = (const float*)d_in[7];
  const float* b_img    = (const float*)d_in[8];
  const float* W_i      = (const float*)d_in[9];
  const float* b_i      = (const float*)d_in[10];
  const float* W1       = (const float*)d_in[11];
  const float* b1       = (const float*)d_in[12];
  const float* W2       = (const float*)d_in[13];
  const float* b2       = (const float*)d_in[14];
  const float* W3       = (const float*)d_in[15];
  const float* b3       = (const float*)d_in[16];
  const float* W_g      = (const float*)d_in[17];
  const float* b_g      = (const float*)d_in[18];

  const int BI = NG * IMG;
  const int ND = N * Dc;
  const int nb = (N + 255) / 256;     // scan blocks

  // ---- workspace layout: common fp32 region, then CSR int region ----
  size_t common = 2*(size_t)ND + E + N + BI + NG*Dc + NG + NG*Dc;   // floats
  size_t csr_i  = (size_t)E + (N+1) + N + N + 256;                   // ints
  size_t need   = common*sizeof(float) + csr_i*sizeof(int);
  if (ws_size < need || nb > 256){
    k_sentinel<<<(out_size+255)/256, 256, 0, stream>>>(out, 690.f, out_size);
    return;
  }

  float* ws    = (float*)d_ws;
  float* xA    = ws;  ws += (size_t)ND;
  float* xw    = ws;  ws += (size_t)ND;
  float* wn    = ws;  ws += E;          // CSR weights
  float* dis   = ws;  ws += N;          // holds deg first, then rsqrt in place
  float* q     = ws;  ws += BI;
  float* pooled= ws;  ws += NG*Dc;
  float* cnt   = ws;  ws += NG;
  float* qi    = ws;  ws += NG*Dc;
  int* iw        = (int*)ws;
  int* es        = iw;  iw += E;        // CSR src indices
  int* row_start = iw;  iw += N+1;
  int* cursor    = iw;  iw += N;
  int* cntN      = iw;  iw += N;
  int* bsum      = iw;  iw += 256;

  float* P = xA;   // image-GEMM partials live in [xA, xA+2*ND+E) BEFORE graph path

  k_init<<<(BI+255)/256, 256, 0, stream>>>(b_img, q, dis, pooled, b_i, qi, cntN, BI, IMG, N);

  // ---- image path first (partials reuse the xA/xw/wn region) ----
  int nseg = IMG / KS3;
  bool v3ok = ((IMG % 512) == 0) && ((size_t)nseg*BI <= 2*(size_t)ND + E);
  if (v3ok){
    k_img_mm3   <<<dim3(IMG/512, nseg), 256, 0, stream>>>(images, W_img, P, IMG);
    k_img_reduce<<<(BI+255)/256, 256, 0, stream>>>(P, q, BI, nseg);
  } else {
    const int KSPLIT = ((IMG % (16*KCH)) == 0) ? 16 : 8;
    k_img_mm_legacy<<<dim3(IMG/256, KSPLIT), 256, 0, stream>>>(images, W_img, q, IMG, IMG/KSPLIT);
  }
  bool ih2 = ((IMG % IKS2) == 0) && (IMG / IKS2 <= 256);
  if (ih2){
    k_ihead_mm2<<<dim3(NG, IKS2), Dc, 0, stream>>>(q, W_i, qi, IMG);
  } else {
    k_ihead_mm <<<dim3(NG, IKS),  Dc, 0, stream>>>(q, W_i, qi, IMG);
  }
  k_ihead_norm<<<NG, Dc, 0, stream>>>(qi, out);

  // ---- graph path ----
  k_gather<<<(ND+255)/256, 256, 0, stream>>>(emb, node_ids, xA, ND);
  k_deg2  <<<(E+255)/256, 256, 0, stream>>>(dst, eattr, dis, cntN, E);
  k_dis   <<<(N+255)/256, 256, 0, stream>>>(dis, N);
  k_scan_partial<<<nb, 256, 0, stream>>>(cntN, bsum, N);
  k_scan_bsum   <<<1,  256, 0, stream>>>(bsum, nb, row_start, N, E);
  k_scan_final  <<<nb, 256, 0, stream>>>(cntN, bsum, row_start, cursor, N);
  k_fill        <<<(E+255)/256, 256, 0, stream>>>(src, dst, eattr, dis, cursor, es, wn, E);

  const float* Wl[3] = {W1, W2, W3};
  const float* bl[3] = {b1, b2, b3};
  for (int l = 0; l < 3; l++){
    k_mm <<<(N+31)/32, 256, 0, stream>>>(xA, Wl[l], xw, N, l > 0);
    k_agg<<<N, Dc, 0, stream>>>(xw, row_start, es, wn, dis, bl[l], xA, N);
  }

  k_pool<<<256, Dc, 0, stream>>>(xA, batch, pooled, cnt, N);
  k_head<<<NG, Dc, 0, stream>>>(pooled, cnt, W_g, b_g, out + NG*Dc);
}